// Round 1
// baseline (1082.389 us; speedup 1.0000x reference)
//
#include <hip/hip_runtime.h>

#define NN 50000
#define NE 800000

// ---------------- kernel 1: edge aggregation for layer 0 --------------------
// one 32-lane group per edge: lane k accumulates edge_attr[e][k] into
// agg_e_sum[dst][k]; lanes 0,1 accumulate node_stats[src][0..1]; lane 0 counts.
__global__ __launch_bounds__(256) void k_edge_agg0(
    const int* __restrict__ ei, const float* __restrict__ ea,
    const float* __restrict__ ns, float* __restrict__ cnt,
    float* __restrict__ agg_h0, float* __restrict__ agg_e) {
  int idx = blockIdx.x * 256 + threadIdx.x;
  int e = idx >> 5, k = idx & 31;
  if (e >= NE) return;
  int d = ei[NE + e];
  atomicAdd(&agg_e[d * 32 + k], ea[e * 32 + k]);
  if (k < 2) {
    int s = ei[e];
    atomicAdd(&agg_h0[d * 2 + k], ns[s * 2 + k]);
  }
  if (k == 0) atomicAdd(&cnt[d], 1.0f);
}

// ---------------- kernel 2: node linear 1 (in=36, out=64) -------------------
// wave handles one node (n uniform per wave), lane = output channel.
__global__ __launch_bounds__(256) void k_node_lin1(
    const float* __restrict__ ns, const float* __restrict__ cnt,
    const float* __restrict__ agg_h0, const float* __restrict__ agg_e,
    const float* __restrict__ W1, const float* __restrict__ b1,
    float* __restrict__ h1) {
  int idx = blockIdx.x * 256 + threadIdx.x;
  int n = idx >> 6, o = idx & 63;
  if (n >= NN) return;
  float inv = 1.0f / fmaxf(cnt[n], 1.0f);
  const float* w = W1 + o * 36;
  float acc = b1[o];
  acc += ns[n * 2 + 0] * w[0] + ns[n * 2 + 1] * w[1];
  acc += agg_h0[n * 2 + 0] * inv * w[2] + agg_h0[n * 2 + 1] * inv * w[3];
#pragma unroll
  for (int k = 0; k < 32; ++k) acc += agg_e[n * 32 + k] * inv * w[4 + k];
  h1[n * 64 + o] = fmaxf(acc, 0.0f);
}

// ---------------- kernel 3: edge aggregation for layer 1 (64 ch) ------------
// one 64-lane wave per edge: coalesced read of h1[src][0..63], atomic add to
// agg_h1[dst][0..63].
__global__ __launch_bounds__(256) void k_edge_agg1(
    const int* __restrict__ ei, const float* __restrict__ h1,
    float* __restrict__ agg_h1) {
  int idx = blockIdx.x * 256 + threadIdx.x;
  int e = idx >> 6, k = idx & 63;
  if (e >= NE) return;
  int s = ei[e], d = ei[NE + e];
  atomicAdd(&agg_h1[d * 64 + k], h1[s * 64 + k]);
}

// ---------------- kernel 4: node linear 2 (in=160, out=64) ------------------
__global__ __launch_bounds__(256) void k_node_lin2(
    const float* __restrict__ h1, const float* __restrict__ cnt,
    const float* __restrict__ agg_h1, const float* __restrict__ agg_e,
    const float* __restrict__ W2, const float* __restrict__ b2,
    float* __restrict__ h2) {
  int idx = blockIdx.x * 256 + threadIdx.x;
  int n = idx >> 6, o = idx & 63;
  if (n >= NN) return;
  float inv = 1.0f / fmaxf(cnt[n], 1.0f);
  const float* w = W2 + o * 160;
  float acc = b2[o];
#pragma unroll
  for (int k = 0; k < 64; ++k) acc += h1[n * 64 + k] * w[k];
#pragma unroll
  for (int k = 0; k < 64; ++k) acc += agg_h1[n * 64 + k] * inv * w[64 + k];
#pragma unroll
  for (int k = 0; k < 32; ++k) acc += agg_e[n * 32 + k] * inv * w[128 + k];
  h2[n * 64 + o] = fmaxf(acc, 0.0f);
}

// ---------------- kernel 5: edge classifier MLP -----------------------------
// thread per edge; acc[64] lives in VGPRs (all indices compile-time);
// weight addresses are wave-uniform -> scalar/broadcast loads.
__global__ __launch_bounds__(256) void k_edge_cls(
    const int* __restrict__ ei, const float* __restrict__ ea,
    const float* __restrict__ h2,
    const float* __restrict__ Wc1, const float* __restrict__ bc1,
    const float* __restrict__ Wc2, const float* __restrict__ bc2,
    const float* __restrict__ Wc3, const float* __restrict__ bc3,
    float* __restrict__ out) {
  int e = blockIdx.x * 256 + threadIdx.x;
  if (e >= NE) return;
  int s = ei[e], d = ei[NE + e];

  float acc[64];
#pragma unroll
  for (int o = 0; o < 64; ++o) acc[o] = bc1[o];

  const float4* hs = (const float4*)(h2 + s * 64);
  const float4* hd = (const float4*)(h2 + d * 64);
  const float4* ev = (const float4*)(ea + e * 32);

  // rep[0:64] = h2[src]
  for (int c = 0; c < 16; ++c) {
    float4 r = hs[c];
#pragma unroll
    for (int o = 0; o < 64; ++o) {
      const float4 w = *(const float4*)(Wc1 + o * 160 + c * 4);
      acc[o] += r.x * w.x + r.y * w.y + r.z * w.z + r.w * w.w;
    }
  }
  // rep[64:128] = h2[dst]
  for (int c = 0; c < 16; ++c) {
    float4 r = hd[c];
#pragma unroll
    for (int o = 0; o < 64; ++o) {
      const float4 w = *(const float4*)(Wc1 + o * 160 + 64 + c * 4);
      acc[o] += r.x * w.x + r.y * w.y + r.z * w.z + r.w * w.w;
    }
  }
  // rep[128:160] = edge_attr
  for (int c = 0; c < 8; ++c) {
    float4 r = ev[c];
#pragma unroll
    for (int o = 0; o < 64; ++o) {
      const float4 w = *(const float4*)(Wc1 + o * 160 + 128 + c * 4);
      acc[o] += r.x * w.x + r.y * w.y + r.z * w.z + r.w * w.w;
    }
  }
#pragma unroll
  for (int o = 0; o < 64; ++o) acc[o] = fmaxf(acc[o], 0.0f);

  float result = bc3[0];
  for (int o = 0; o < 32; ++o) {  // o uniform -> scalar weight loads
    float t = bc2[o];
#pragma unroll
    for (int i = 0; i < 64; ++i) t += acc[i] * Wc2[o * 64 + i];
    result += fmaxf(t, 0.0f) * Wc3[o];
  }
  out[e] = result;
}

extern "C" void kernel_launch(void* const* d_in, const int* in_sizes, int n_in,
                              void* d_out, int out_size, void* d_ws, size_t ws_size,
                              hipStream_t stream) {
  // inputs: 0:x(unused) 1:edge_index 2:edge_attr 3:node_stats 4:W1 5:b1 6:W2
  //         7:b2 8:Wc1 9:bc1 10:Wc2 11:bc2 12:Wc3 13:bc3
  const int*   ei  = (const int*)d_in[1];
  const float* ea  = (const float*)d_in[2];
  const float* ns  = (const float*)d_in[3];
  const float* W1  = (const float*)d_in[4];
  const float* b1  = (const float*)d_in[5];
  const float* W2  = (const float*)d_in[6];
  const float* b2  = (const float*)d_in[7];
  const float* Wc1 = (const float*)d_in[8];
  const float* bc1 = (const float*)d_in[9];
  const float* Wc2 = (const float*)d_in[10];
  const float* bc2 = (const float*)d_in[11];
  const float* Wc3 = (const float*)d_in[12];
  const float* bc3 = (const float*)d_in[13];
  float* out = (float*)d_out;

  // workspace layout (floats):
  //   cnt     [NN]      @ 0
  //   agg_h0  [2*NN]    @ NN
  //   agg_e   [32*NN]   @ 3*NN
  //   agg_h1  [64*NN]   @ 35*NN
  //   h1      [64*NN]   @ 99*NN
  //   h2      [64*NN]   @ 163*NN      (total 227*NN floats = 45.4 MB)
  float* ws     = (float*)d_ws;
  float* cnt    = ws;
  float* agg_h0 = ws + (size_t)NN;
  float* agg_e  = ws + (size_t)3 * NN;
  float* agg_h1 = ws + (size_t)35 * NN;
  float* h1     = ws + (size_t)99 * NN;
  float* h2     = ws + (size_t)163 * NN;

  // zero the atomic-accumulation region (cnt..agg_h1) every call
  hipMemsetAsync(d_ws, 0, (size_t)99 * NN * sizeof(float), stream);

  k_edge_agg0<<<(NE * 32) / 256, 256, 0, stream>>>(ei, ea, ns, cnt, agg_h0, agg_e);
  k_node_lin1<<<(NN * 64 + 255) / 256, 256, 0, stream>>>(ns, cnt, agg_h0, agg_e, W1, b1, h1);
  k_edge_agg1<<<(NE * 64) / 256, 256, 0, stream>>>(ei, h1, agg_h1);
  k_node_lin2<<<(NN * 64 + 255) / 256, 256, 0, stream>>>(h1, cnt, agg_h1, agg_e, W2, b2, h2);
  k_edge_cls<<<(NE + 255) / 256, 256, 0, stream>>>(ei, ea, h2, Wc1, bc1, Wc2, bc2, Wc3, bc3, out);
}